// Round 3
// 579.888 us; speedup vs baseline: 1.1732x; 1.1732x over previous
//
#include <hip/hip_runtime.h>
#include <math.h>

#define L_SPH 7
#define K_RAD 6
#define LK    42          // L*K
#define TPB   256         // edge-kernel block
#define PTPB  64          // pair-kernel block: 1 wave -> 10.75KB LDS -> 15 blocks/CU
#define RSTR  48          // rbf row stride (floats): 192B, 16B-aligned; [0..41]=rbf,
                          // [42..44]=normalized dir, [45..47]=pad. 192B rows always
                          // touch exactly 2 cachelines on the random gather.

// clang ext-vector types: __builtin_nontemporal_store requires scalar or NATIVE
// vector types — HIP_vector_type (float4/float2) is rejected (round-2 compile
// error). These are layout-identical to float4/float2.
typedef float f32x4 __attribute__((ext_vector_type(4)));
typedef float f32x2 __attribute__((ext_vector_type(2)));

// ---------------- host-side constants (replicates numpy bisection exactly) ---
// The reference casts Z and NORM to float32 (jnp.asarray(..., float32)); we do
// the bisection in f64 (bit-matching the reference host code) then round.

struct SBConsts {
    float z[L_SPH][K_RAD];     // Bessel zeros z_{l,n}, rounded to f32 like ref
    float nrm[L_SPH][K_RAD];   // normalizers c_{l,n}, rounded to f32 like ref
    float sphc[L_SPH];         // sqrt((2l+1)/4pi), f32
};

static double host_sph_jn(double r, int l) {
    double j = sin(r) / r;
    if (l == 0) return j;
    double jp = sin(r) / (r * r) - cos(r) / r;
    for (int i = 1; i < l; i++) {
        double t = (2.0 * i + 1.0) / r * jp - j;
        j = jp; jp = t;
    }
    return jp;
}

static SBConsts make_consts() {
    const int L = L_SPH, K = K_RAD;
    double prev[L + K];
    for (int i = 0; i < L + K; i++) prev[i] = (i + 1) * M_PI;
    int plen = L + K;
    double zeros[L_SPH][K_RAD];
    for (int n = 0; n < K; n++) zeros[0][n] = prev[n];
    for (int l = 1; l < L; l++) {
        int m = plen - 1;
        double lo[L + K], hi[L + K], flo[L + K];
        for (int i = 0; i < m; i++) {
            lo[i] = prev[i]; hi[i] = prev[i + 1];
            flo[i] = host_sph_jn(lo[i], l);
        }
        for (int it = 0; it < 100; it++) {
            for (int i = 0; i < m; i++) {
                double mid = 0.5 * (lo[i] + hi[i]);
                double fm  = host_sph_jn(mid, l);
                bool same  = (fm >= 0.0) == (flo[i] >= 0.0);
                if (same) { lo[i] = mid; flo[i] = fm; }
                else      { hi[i] = mid; }
            }
        }
        for (int i = 0; i < m; i++) prev[i] = 0.5 * (lo[i] + hi[i]);
        plen = m;
        for (int n = 0; n < K; n++) zeros[l][n] = prev[n];
    }
    SBConsts c;
    for (int l = 0; l < L; l++) {
        for (int n = 0; n < K; n++) {
            c.z[l][n] = (float)zeros[l][n];
            double j1 = host_sph_jn(zeros[l][n], l + 1);
            c.nrm[l][n] = (float)(1.0 / sqrt(0.5 * j1 * j1));
        }
        c.sphc[l] = (float)sqrt((2.0 * l + 1.0) / (4.0 * M_PI));
    }
    return c;
}

// ---------------- device helpers --------------------------------------------

// Correctly-rounded float32 sin/cos: evaluate in f64 (ocml, ~0.5 ulp f64) and
// round once to f32. Proxy for numpy's float32 trig (near-correctly-rounded at
// the small arguments that dominate the amplified entries).
// sincos shares one argument reduction + core -> ~half the trig cost of
// separate sin+cos; any last-f64-ulp deviation vs sin()/cos() flips the f32
// rounding with probability ~2^-29 (harmless at the check's tolerance).
__device__ __forceinline__ float sin_f32cr(float t) { return (float)sin((double)t); }
__device__ __forceinline__ void sincos_f32cr(float t, float& s, float& c) {
    double ds, dc;
    sincos((double)t, &ds, &dc);
    s = (float)ds; c = (float)dc;
}

// Bit-replicates the numpy float32 pipeline per edge:
//   dist = sqrt((dx*dx + dy*dy) + dz*dz)           (f32 each step)
//   x = dist/5 ; t = x*z32[l][n]
//   j0 = sin/t ; j1 = sin/t^2 - cos/t
//   j,jp = jp, ((2i+1)/t)*jp - j                   (div, mul, sub — NO fma)
//   rbf = (norm32*j) * env
// #pragma clang fp contract(off) prevents HIP's default fma contraction, which
// would change rounding and decorrelate the amplified (unstable) entries.
__device__ void edge_row_f32(float dx, float dy, float dz, const SBConsts& c,
                             float* row, float& nx, float& ny, float& nz) {
#pragma clang fp contract(off)
    float s = dx * dx;
    s = s + dy * dy;
    s = s + dz * dz;
    float dist = (float)sqrt((double)s);   // correctly-rounded f32 sqrt
    nx = dx / dist; ny = dy / dist; nz = dz / dist;
    float x = dist / 5.0f;                 // CUTOFF = 5
    // envelope p=6: 1/x - 28 x^5 + 48 x^6 - 21 x^7 (term order as reference;
    // not on the amplified path — last-ulp pow differences are harmless)
    float x2 = x * x, x4 = x2 * x2;
    float x5 = x4 * x, x6 = x5 * x, x7 = x6 * x;
    float env = 1.0f / x;
    env = env + (-28.0f) * x5;
    env = env + 48.0f * x6;
    env = env + (-21.0f) * x7;
#pragma unroll
    for (int l = 0; l < L_SPH; l++) {
#pragma unroll
        for (int n = 0; n < K_RAD; n++) {
            float t  = x * c.z[l][n];
            float sn, co;
            if (l == 0) { sn = sin_f32cr(t); co = 0.0f; }  // cos unused at l=0
            else        { sincos_f32cr(t, sn, co); }
            float j  = sn / t;                 // j_0
            if (l > 0) {
                float t2 = t * t;
                float a1 = sn / t2;
                float a2 = co / t;
                float jp = a1 - a2;            // j_1 (cancellation preserved)
#pragma unroll
                for (int i = 1; i < l; i++) {
                    float q  = (float)(2 * i + 1) / t;
                    float m  = q * jp;
                    float nj = m - j;
                    j = jp; jp = nj;
                }
                j = jp;
            }
            float rb = c.nrm[l][n] * j;
            row[l * K_RAD + n] = rb * env;
        }
    }
}

__device__ __forceinline__ void legendre_cbf(float cs, const float* sphc,
                                             float* cbf) {
#pragma clang fp contract(off)
    float P0 = 1.0f, P1 = cs;
    cbf[0] = sphc[0];
    cbf[1] = sphc[1] * cs;
#pragma unroll
    for (int l = 1; l < L_SPH - 1; l++) {
        float a  = (float)(2 * l + 1) * cs;    // ((2l+1)*cos)*P_cur - l*P_prev
        float b  = a * P1;
        float d  = b - (float)l * P0;
        float Pn = d / (float)(l + 1);
        P0 = P1; P1 = Pn;
        cbf[l + 1] = sphc[l + 1] * Pn;
    }
}

// ---------------- kernel 1: per-edge rbf row (+packed dir) -------------------

__global__ __launch_bounds__(TPB) void edge_kernel(
        const float* __restrict__ d, float* __restrict__ rbf,
        float4* __restrict__ nd4, int nE, SBConsts c) {
    int e = blockIdx.x * TPB + threadIdx.x;
    if (e >= nE) return;
    float dx = d[3 * e], dy = d[3 * e + 1], dz = d[3 * e + 2];
    float row[LK], nx, ny, nz;
    edge_row_f32(dx, dy, dz, c, row, nx, ny, nz);
    nd4[e] = make_float4(nx, ny, nz, 0.0f);          // receiver-side gather table
    float4* o = (float4*)(rbf + (size_t)e * RSTR);   // 192B rows, 16B aligned
#pragma unroll
    for (int q = 0; q < 10; q++)
        o[q] = make_float4(row[4 * q], row[4 * q + 1], row[4 * q + 2], row[4 * q + 3]);
    o[10] = make_float4(row[40], row[41], nx, ny);   // sender dir rides in the row
    o[11] = make_float4(nz, 0.0f, 0.0f, 0.0f);
}

// ---------------- kernel 2: per-pair gather + Legendre + outer product -------
// 1 wave/block. LDS is an UNPADDED exact image of the block's output region:
//  - float2 LDS writes at dword-stride 42 are 2-way bank aliased (free),
//  - copy-out is a straight float4 memcpy (coalesced, no div/mod),
//  - 10,752 B LDS -> 15 blocks/CU (vs 3 at the old 44KB) for gather-latency
//    hiding; no cross-wave __syncthreads coupling.

__global__ __launch_bounds__(PTPB, 4) void pair_kernel(
        const int* __restrict__ snd, const int* __restrict__ rcv,
        const float* __restrict__ rbf, const float4* __restrict__ nd4,
        float* __restrict__ out, int nP, SBConsts c) {
#pragma clang fp contract(off)
    __shared__ float so[PTPB * LK];                  // 10,752 B
    int p = blockIdx.x * PTPB + threadIdx.x;
    if (p < nP) {
        int s = snd[p], r = rcv[p];
        const float4* rowp = (const float4*)(rbf + (size_t)s * RSTR);
        float4 v[12];
#pragma unroll
        for (int q = 0; q < 12; q++) v[q] = rowp[q]; // 12x dwordx4, exactly 2 lines
        float4 b = nd4[r];
        float ax = v[10].z, ay = v[10].w, az = v[11].x;   // sender dir (same bits
        float cs = ax * b.x;                              //  as nd4[s])
        cs = cs + ay * b.y;                        // left-to-right like einsum
        cs = cs + az * b.z;
        float cbf[L_SPH];
        legendre_cbf(cs, c.sphc, cbf);
        float2* my = (float2*)&so[threadIdx.x * LK];      // 168B row, 8B aligned
#pragma unroll
        for (int q = 0; q < 10; q++) {
            float4 vq = v[q];
            my[2 * q]     = make_float2(vq.x * cbf[(4 * q + 0) / K_RAD],
                                        vq.y * cbf[(4 * q + 1) / K_RAD]);
            my[2 * q + 1] = make_float2(vq.z * cbf[(4 * q + 2) / K_RAD],
                                        vq.w * cbf[(4 * q + 3) / K_RAD]);
        }
        my[20] = make_float2(v[10].x * cbf[6], v[10].y * cbf[6]);  // j=40,41
    }
    __syncthreads();                                 // single wave: near-free
    size_t base  = (size_t)blockIdx.x * (PTPB * LK);
    size_t limit = (size_t)nP * LK;
    if (base + PTPB * LK <= limit) {
        // fast path: LDS image == output region; 10x float4 + 1x float2 per lane
        // (nontemporal via ext-vector types — clang rejects HIP_vector_type)
        f32x4* o4 = (f32x4*)(out + base);            // base = blk*10752B, 16B ok
        const f32x4* s4 = (const f32x4*)so;
#pragma unroll
        for (int k = 0; k < 10; k++)
            __builtin_nontemporal_store(s4[threadIdx.x + k * PTPB],
                                        &o4[threadIdx.x + k * PTPB]);
        f32x2* o2 = (f32x2*)(out + base + 2560);     // floats 2560..2687
        const f32x2* s2 = (const f32x2*)(so + 2560);
        __builtin_nontemporal_store(s2[threadIdx.x], &o2[threadIdx.x]);
    } else {
        for (int k = 0; k < LK; k++) {
            size_t g = base + threadIdx.x + (size_t)k * PTPB;
            if (g < limit) out[g] = so[threadIdx.x + k * PTPB];
        }
    }
}

// ---------------- fallback: fully fused per-pair (no workspace) --------------

__global__ __launch_bounds__(TPB) void fused_kernel(
        const float* __restrict__ d, const int* __restrict__ snd,
        const int* __restrict__ rcv, float* __restrict__ out,
        int nP, SBConsts c) {
#pragma clang fp contract(off)
    int p = blockIdx.x * TPB + threadIdx.x;
    if (p >= nP) return;
    int s = snd[p], r = rcv[p];
    float row[LK], sx, sy, sz;
    edge_row_f32(d[3 * s], d[3 * s + 1], d[3 * s + 2], c, row, sx, sy, sz);
    float rx = d[3 * r], ry = d[3 * r + 1], rz = d[3 * r + 2];
    float t = rx * rx;  t = t + ry * ry;  t = t + rz * rz;
    float rd = (float)sqrt((double)t);
    float cs = sx * (rx / rd);
    cs = cs + sy * (ry / rd);
    cs = cs + sz * (rz / rd);
    float cbf[L_SPH];
    legendre_cbf(cs, c.sphc, cbf);
    float* o = out + (size_t)p * LK;
#pragma unroll
    for (int j = 0; j < LK; j++) o[j] = row[j] * cbf[j / K_RAD];
}

// ---------------- launch -----------------------------------------------------

extern "C" void kernel_launch(void* const* d_in, const int* in_sizes, int n_in,
                              void* d_out, int out_size, void* d_ws, size_t ws_size,
                              hipStream_t stream) {
    static SBConsts c = make_consts();   // host-side lazy init; same device work every call
    const float* dists = (const float*)d_in[0];
    const int*   snd   = (const int*)d_in[1];
    const int*   rcv   = (const int*)d_in[2];
    float*       out   = (float*)d_out;
    int nE = in_sizes[0] / 3;
    int nP = in_sizes[1];

    size_t rbf_bytes = (size_t)nE * RSTR * sizeof(float);   // 192B rows (16B mult)
    size_t need = rbf_bytes + (size_t)nE * sizeof(float4);

    if (ws_size >= need) {
        float*  rbf = (float*)d_ws;
        float4* nd4 = (float4*)((char*)d_ws + rbf_bytes);
        edge_kernel<<<(nE + TPB - 1) / TPB, TPB, 0, stream>>>(dists, rbf, nd4, nE, c);
        pair_kernel<<<(nP + PTPB - 1) / PTPB, PTPB, 0, stream>>>(snd, rcv, rbf, nd4, out, nP, c);
    } else {
        fused_kernel<<<(nP + TPB - 1) / TPB, TPB, 0, stream>>>(dists, snd, rcv, out, nP, c);
    }
}